// Round 19
// baseline (81.856 us; speedup 1.0000x reference)
//
#include <hip/hip_runtime.h>
#include <cmath>

// TensorTrainGaussian: v <- (softmax_b(W_m) * NormalPDF(x_m)) @ v, M=32 steps of
// 16x16, N=131072.
//
// REVISED MODEL (r17 post-mortem): VALUBusy is an any-of-4-SIMD per-CU metric.
// Refit: r1's 86% -> per-SIMD 39% (14 cyc/elem = exact hand count); r17's 65%
// -> per-SIMD ~28%. Kernel is LATENCY/DRAIN-bound: avg occupancy 21% vs 50%
// LDS cap (512 fat blocks -> coarse drain), and 32 samples/wave makes the
// wave-granular early exit wait on max-of-32 (r16/r17 regression source).
//
// r18/r19: 1 sample/lane (16 samples/wave exit), block=256 (2048 blocks, 4
//   resident/CU, fine drain), 8192 waves. Math core unchanged: deferred
//   quad_perm DPP broadcast of prev-v (template<H> a_group — r18's compile
//   fix: H must be a template param, not a runtime unroll var), plain
//   v_pk_fma_f32 (b-pairs naturally even-aligned), saturating-cvt Schraudolph
//   exp2, laundered LDS bases, exit check every 2 steps via quad DPP reduce.
// Early exit (provable): softmax cols sum to 1, pdf<=0.798 => sum(v) shrinks
//   x0.798/step; at <5e-17 final log(lik+eps) within 0.21 of ref floor
//   (tol 0.72).

#define TT_N 131072
#define TT_M 32

typedef float v2f __attribute__((ext_vector_type(2)));
typedef float v4f __attribute__((ext_vector_type(4)));

// ws layout (floats): z[16] | P'[256] | Q'[256] | R'[32*256], tables [a*16+b]
#define WS_Z 0
#define WS_P 16
#define WS_Q (16 + 256)
#define WS_R (16 + 512)
#define TBL_FLOATS (512 + 8192)

__global__ __launch_bounds__(512) void tt_prep(const float* __restrict__ Wk0,
                                               const float* __restrict__ W,
                                               const float* __restrict__ mu,
                                               const float* __restrict__ sigma,
                                               float* __restrict__ ws) {
    const int t = threadIdx.x;
    const float LOG2E = 1.4426950408889634f;
    const float SCALE = 8388608.0f;               // 2^23
    const float BIAS  = 126.94242f;               // 127 - 0.0575812 (mean-one c)
    float* z  = ws + WS_Z;
    float* PP = ws + WS_P;
    float* QQ = ws + WS_Q;
    float* RT = ws + WS_R;

    if (t < 16) {
        float mx = -1e30f;
        for (int i = 0; i < 16; ++i) mx = fmaxf(mx, Wk0[i]);
        float se = 0.f;
        for (int i = 0; i < 16; ++i) se += __expf(Wk0[i] - mx);
        z[t] = __expf(Wk0[t] - mx) / se;
    }

    if (t < 256) {
        const int a = t >> 4, b = t & 15;     // transposed [a][b]
        float s  = sigma[b * 16 + a];
        float mm = mu[b * 16 + a];
        float c2 = 0.72134752044448f / (s * s);   // 0.5*log2(e)/sigma^2
        PP[a * 16 + b] = -c2 * SCALE;
        QQ[a * 16 + b] = 2.0f * c2 * mm * SCALE;
    }

    // one thread per (m, a): column softmax over b of W[m, b, a]
    const int m = t >> 4;
    const int a = t & 15;
    const float* Wc = W + m * 256 + a;  // stride 16 over b
    float mx = -1e30f;
    #pragma unroll
    for (int b = 0; b < 16; ++b) mx = fmaxf(mx, Wc[b * 16]);
    float se = 0.f;
    #pragma unroll
    for (int b = 0; b < 16; ++b) se += __expf(Wc[b * 16] - mx);
    float lse = __log2f(se);
    #pragma unroll
    for (int b = 0; b < 16; ++b) {
        float s     = sigma[b * 16 + a];
        float mm    = mu[b * 16 + a];
        float inv_s = 1.0f / s;
        float c2    = 0.72134752044448f / (s * s);
        float lw    = (Wc[b * 16] - mx) * LOG2E - lse;   // log2 softmax weight
        float R = lw + __log2f(inv_s * 0.3989422804014327f) - c2 * mm * mm;
        RT[m * 256 + a * 16 + b] = (R + BIAS) * SCALE;
    }
}

template <int CTRL>
static __device__ __forceinline__ float dpp_f(float x) {
    return __int_as_float(
        __builtin_amdgcn_mov_dpp(__float_as_int(x), CTRL, 0xF, 0xF, 1));
}

// Real packed fma: all operands v2f -> even-aligned VGPR pairs (r15-proven)
static __device__ __forceinline__ v2f pk_fma(v2f a, v2f b, v2f c) {
    v2f d;
    asm("v_pk_fma_f32 %0, %1, %2, %3" : "=v"(d) : "v"(a), "v"(b), "v"(c));
    return d;
}

// Schraudolph exp2 of prescaled value; cvt_u32 saturates s<0 -> 0 -> e=0.0f
static __device__ __forceinline__ float cvt_exp(float s) {
    unsigned u;
    asm("v_cvt_u32_f32 %0, %1" : "=v"(u) : "v"(s));
    return __uint_as_float(u);
}

// One a-group: 4 a-iters with va fetched from quad-lane H via DPP broadcast.
// H must be a TEMPLATE param (DPP ctrl is an immediate) — r18 compile fix.
template <int H>
static __device__ __forceinline__ void a_group(const float* __restrict__ prev,
                                               float& n0, float& n1,
                                               float& n2, float& n3,
                                               v2f xx, v2f xx2,
                                               const float* __restrict__ Pm,
                                               const float* __restrict__ Qm,
                                               const float* __restrict__ Rm,
                                               int boff) {
    #pragma unroll
    for (int j = 0; j < 4; ++j) {
        const int a = H * 4 + j;
        const float va = dpp_f<H * 0x55>(prev[j]);  // quad_perm [H,H,H,H]
        v4f P4 = *(const v4f*)(Pm + a * 16 + boff);
        v4f Q4 = *(const v4f*)(Qm + a * 16 + boff);
        v4f R4 = *(const v4f*)(Rm + a * 16);
        v2f s0 = pk_fma(P4.xy, xx2, pk_fma(Q4.xy, xx, R4.xy));
        v2f s1 = pk_fma(P4.zw, xx2, pk_fma(Q4.zw, xx, R4.zw));
        n0 = __fmaf_rn(va, cvt_exp(s0.x), n0);
        n1 = __fmaf_rn(va, cvt_exp(s0.y), n1);
        n2 = __fmaf_rn(va, cvt_exp(s1.x), n2);
        n3 = __fmaf_rn(va, cvt_exp(s1.y), n3);
    }
}

// One TT step: prev[4] (own 4 b comps) -> next[4]; va via quad DPP broadcast
static __device__ __forceinline__ void tt_step(const float* __restrict__ prev,
                                               float* __restrict__ next,
                                               float xm,
                                               const float* __restrict__ lds,
                                               int m, int boff) {
    const float xq = xm * xm;
    const v2f xx  = {xm, xm};
    const v2f xx2 = {xq, xq};

    int lo = 0;
    asm volatile("" : "+v"(lo));     // launder: block LICM / hoisting
    const float* Pm = lds + lo;
    const float* Qm = lds + 256 + lo;
    const float* Rm = lds + 512 + m * 256 + boff + lo;

    float n0 = 0.f, n1 = 0.f, n2 = 0.f, n3 = 0.f;
    a_group<0>(prev, n0, n1, n2, n3, xx, xx2, Pm, Qm, Rm, boff);
    a_group<1>(prev, n0, n1, n2, n3, xx, xx2, Pm, Qm, Rm, boff);
    a_group<2>(prev, n0, n1, n2, n3, xx, xx2, Pm, Qm, Rm, boff);
    a_group<3>(prev, n0, n1, n2, n3, xx, xx2, Pm, Qm, Rm, boff);
    next[0] = n0; next[1] = n1; next[2] = n2; next[3] = n3;
}

__global__ __launch_bounds__(256) void tt_main(const float* __restrict__ X,
                                               const float* __restrict__ ws,
                                               float* __restrict__ out) {
    __shared__ float lds[TBL_FLOATS];   // P'[256] | Q'[256] | R'[8192]
    {
        const v4f* src = (const v4f*)(ws + WS_P);
        v4f* dst = (v4f*)lds;
        for (int i = threadIdx.x; i < TBL_FLOATS / 4; i += 256) dst[i] = src[i];
    }
    __syncthreads();

    const int tid  = blockIdx.x * 256 + threadIdx.x;
    const int n    = tid >> 2;          // 4 lanes per sample
    const int g    = tid & 3;           // b-group: own b in [4g, 4g+4)
    const int boff = g << 2;

    const float* zp = ws + WS_Z;
    float A[4], B[4];                    // own 4 components
    #pragma unroll
    for (int j = 0; j < 4; ++j) A[j] = zp[boff + j];

    const float* xp = X + (size_t)n * TT_M;
    float S = 1.f;
    v2f xc = *(const v2f*)xp;            // x for steps {0,1}

    #pragma unroll 1
    for (int mo = 0; mo < 16; ++mo) {
        const int nx = (2 * mo + 2 < TT_M) ? 2 * mo + 2 : TT_M - 2;
        v2f xn = *(const v2f*)(xp + nx); // prefetch next x pair under compute

        tt_step(A, B, xc.x, lds, 2 * mo, boff);
        tt_step(B, A, xc.y, lds, 2 * mo + 1, boff);

        // exit check every 2 steps: exact sum via quad DPP-add reduce
        float part = (A[0] + A[1]) + (A[2] + A[3]);
        part += dpp_f<0xB1>(part);       // + xor1 neighbor
        part += dpp_f<0x4E>(part);       // + xor2 neighbor
        S = part;
        if (__all(S < 5e-17f)) break;

        xc = xn;
    }

    if (g == 0) out[n] = logf(S + 2.2204460492503131e-16f);
}

extern "C" void kernel_launch(void* const* d_in, const int* in_sizes, int n_in,
                              void* d_out, int out_size, void* d_ws, size_t ws_size,
                              hipStream_t stream) {
    const float* X     = (const float*)d_in[0];
    const float* Wk0   = (const float*)d_in[1];
    const float* W     = (const float*)d_in[2];
    const float* mu    = (const float*)d_in[3];
    const float* sigma = (const float*)d_in[4];
    float* out = (float*)d_out;
    float* ws  = (float*)d_ws;

    tt_prep<<<1, 512, 0, stream>>>(Wk0, W, mu, sigma, ws);
    tt_main<<<(TT_N * 4) / 256, 256, 0, stream>>>(X, ws, out);
}